// Round 1
// baseline (333.332 us; speedup 1.0000x reference)
//
#include <hip/hip_runtime.h>
#include <hip/hip_bf16.h>

typedef unsigned short u16;
typedef __attribute__((ext_vector_type(8))) __bf16 bf16x8;
typedef __attribute__((ext_vector_type(4))) float f32x4;

#define DEV static __device__ __forceinline__

DEV u16 f2bf(float f) {
  union { float f; unsigned u; } c; c.f = f;
  unsigned r = c.u + 0x7fffu + ((c.u >> 16) & 1u);
  return (u16)(r >> 16);
}
DEV float fsig(float x) { return 1.f / (1.f + __expf(-x)); }

DEV void gload_lds16(const void* g, void* l) {
  __builtin_amdgcn_global_load_lds(
      (const __attribute__((address_space(1))) void*)g,
      (__attribute__((address_space(3))) void*)l, 16, 0, 0);
}

// fp32 -> bf16 elementwise (RNE), float4-vectorized
__global__ void cvt_bf16(const float4* __restrict__ src, u16* __restrict__ dst, int n4) {
  int i = blockIdx.x * blockDim.x + threadIdx.x;
  int stride = gridDim.x * blockDim.x;
  for (; i < n4; i += stride) {
    float4 v = src[i];
    union { u16 s[4]; unsigned long long q; } o;
    o.s[0] = f2bf(v.x); o.s[1] = f2bf(v.y); o.s[2] = f2bf(v.z); o.s[3] = f2bf(v.w);
    *(unsigned long long*)&dst[(size_t)i * 4] = o.q;
  }
}

// 64x64-tile bf16 transpose: VT[d][k] = V[k][d], per batch (blockIdx.z)
__global__ __launch_bounds__(256) void transpose_bf16(
    const u16* __restrict__ V, u16* __restrict__ VT, int rows, int cols) {
  __shared__ u16 t[64][80];
  const u16* Vb = V + (size_t)blockIdx.z * rows * cols;
  u16* VTb = VT + (size_t)blockIdx.z * rows * cols;
  const int kb = blockIdx.x * 64, db = blockIdx.y * 64;
  const int tid = threadIdx.x;
  const int r = tid >> 3, c8 = (tid & 7) * 8;
#pragma unroll
  for (int it = 0; it < 2; it++) {
    int rr = r + it * 32;
    *(uint4*)&t[rr][c8] = *(const uint4*)&Vb[(size_t)(kb + rr) * cols + db + c8];
  }
  __syncthreads();
#pragma unroll
  for (int it = 0; it < 2; it++) {
    int d = (tid >> 3) + it * 32;
    int k0 = (tid & 7) * 8;
    union { u16 s[8]; uint4 q; } o;
#pragma unroll
    for (int j = 0; j < 8; j++) o.s[j] = t[k0 + j][d];
    *(uint4*)&VTb[(size_t)(db + d) * rows + kb + k0] = o.q;
  }
}

// C[M,N] = A[M,K] * Bt[N,K]^T  (bf16 in, fp32 acc), 128x128 tile, BK=64, 4 waves.
// EPI 0: QKV (z=blockIdx.z selects W/bias/out; Q scaled 1/32) -> bf16
// EPI 1: scores: sigmoid(sigmoid(acc)*mask) -> bf16   (mask ld = N)
// EPI 2: plain fp32 out
template <int EPI>
__global__ __launch_bounds__(256, 2) void gemm_bt(
    const u16* __restrict__ A, const u16* __restrict__ Bt,
    u16* __restrict__ Cb, float* __restrict__ Cf,
    const float* __restrict__ bias0, const float* __restrict__ bias1,
    const float* __restrict__ bias2, const float* __restrict__ mask,
    int M, int N, int K) {
  __shared__ __align__(16) u16 As[128 * 64];
  __shared__ __align__(16) u16 Bs[128 * 64];

  const int bm = blockIdx.x, bn = blockIdx.y, z = blockIdx.z;
  if (EPI == 0) Bt += (size_t)z * N * K;
  const float* bias = (EPI == 0) ? (z == 0 ? bias0 : (z == 1 ? bias1 : bias2)) : nullptr;
  const float scale = (EPI == 0 && z == 0) ? 0.03125f : 1.0f;

  const int tid = threadIdx.x;
  const int wid = tid >> 6, lane = tid & 63;
  const int wr = wid >> 1, wc = wid & 1;
  const int l3 = lane >> 3, sl = lane & 7;
  const int srcslot = sl ^ l3;  // pre-swizzled global source slot (rule #21)

  const u16* Ag = A + (size_t)(bm * 128 + wid * 32 + l3) * K + srcslot * 8;
  const u16* Bg = Bt + (size_t)(bn * 128 + wid * 32 + l3) * K + srcslot * 8;
  u16* AsW = &As[wid * 32 * 64];
  u16* BsW = &Bs[wid * 32 * 64];

  f32x4 acc[4][4];
#pragma unroll
  for (int i = 0; i < 4; i++)
#pragma unroll
    for (int j = 0; j < 4; j++) acc[i][j] = (f32x4)(0.f);

  const int fr = lane & 15, kq = lane >> 4;

  for (int kt = 0; kt < K; kt += 64) {
#pragma unroll
    for (int i = 0; i < 4; i++) {
      gload_lds16(Ag + kt + i * 8 * K, AsW + i * 8 * 64);
      gload_lds16(Bg + kt + i * 8 * K, BsW + i * 8 * 64);
    }
    __syncthreads();
#pragma unroll
    for (int ks = 0; ks < 2; ks++) {
      bf16x8 af[4], bfr[4];
#pragma unroll
      for (int i = 0; i < 4; i++) {
        const int ra = wr * 64 + i * 16 + fr;
        af[i] = *(const bf16x8*)&As[ra * 64 + (((ks * 4 + kq) ^ (ra & 7)) * 8)];
        const int rb = wc * 64 + i * 16 + fr;
        bfr[i] = *(const bf16x8*)&Bs[rb * 64 + (((ks * 4 + kq) ^ (rb & 7)) * 8)];
      }
#pragma unroll
      for (int i = 0; i < 4; i++)
#pragma unroll
        for (int j = 0; j < 4; j++)
          acc[i][j] = __builtin_amdgcn_mfma_f32_16x16x32_bf16(af[i], bfr[j], acc[i][j], 0, 0, 0);
    }
    __syncthreads();
  }

  const int rbase = bm * 128 + wr * 64;
  const int cbase = bn * 128 + wc * 64;
#pragma unroll
  for (int i = 0; i < 4; i++)
#pragma unroll
    for (int j = 0; j < 4; j++) {
      const int col = cbase + j * 16 + fr;
#pragma unroll
      for (int r = 0; r < 4; r++) {
        const int row = rbase + i * 16 + kq * 4 + r;
        float v = acc[i][j][r];
        if (EPI == 0) {
          v = (v + bias[col]) * scale;
          Cb[(size_t)z * M * N + (size_t)row * N + col] = f2bf(v);
        } else if (EPI == 1) {
          float m = mask[(size_t)row * N + col];
          Cb[(size_t)row * N + col] = f2bf(fsig(fsig(v) * m));
        } else {
          Cf[(size_t)row * N + col] = v;
        }
      }
    }
}

extern "C" void kernel_launch(void* const* d_in, const int* in_sizes, int n_in,
                              void* d_out, int out_size, void* d_ws, size_t ws_size,
                              hipStream_t stream) {
  const int B = 2, S = 4096, D = 1024;
  const float* hid  = (const float*)d_in[0];
  const float* mask = (const float*)d_in[1];
  const float* Wq = (const float*)d_in[2];
  const float* bq = (const float*)d_in[3];
  const float* Wk = (const float*)d_in[4];
  const float* bk = (const float*)d_in[5];
  const float* Wv = (const float*)d_in[6];
  const float* bv = (const float*)d_in[7];

  const size_t MT = (size_t)B * S * D;  // 8388608 tokens*dim
  u16* hbf = (u16*)d_ws;                // MT
  u16* wbf = hbf + MT;                  // 3*D*D
  u16* Qb  = wbf + 3 * (size_t)D * D;   // MT  (Q,K,V contiguous: EPI0 z-offset)
  u16* Kb  = Qb + MT;
  u16* Vb  = Kb + MT;
  u16* VTb = Vb + MT;                   // MT
  u16* Pb  = VTb + MT;                  // S*S (single batch, reused)

  // 1. converts
  cvt_bf16<<<2048, 256, 0, stream>>>((const float4*)hid, hbf, (int)(MT / 4));
  cvt_bf16<<<512, 256, 0, stream>>>((const float4*)Wq, wbf, D * D / 4);
  cvt_bf16<<<512, 256, 0, stream>>>((const float4*)Wk, wbf + (size_t)D * D, D * D / 4);
  cvt_bf16<<<512, 256, 0, stream>>>((const float4*)Wv, wbf + 2 * (size_t)D * D, D * D / 4);

  // 2. fused QKV projection: [8192,1024] x [1024,1024]^T, z = Q/K/V
  gemm_bt<0><<<dim3(B * S / 128, D / 128, 3), 256, 0, stream>>>(
      hbf, wbf, Qb, nullptr, bq, bk, bv, nullptr, B * S, D, D);

  // 3. V transpose per batch: VT[d][k]
  transpose_bf16<<<dim3(S / 64, D / 64, B), 256, 0, stream>>>(Vb, VTb, S, D);

  // 4. per batch: scores(+sigmoid sigmoid mask) then P*V
  for (int b = 0; b < B; b++) {
    gemm_bt<1><<<dim3(S / 128, S / 128), 256, 0, stream>>>(
        Qb + (size_t)b * S * D, Kb + (size_t)b * S * D, Pb, nullptr,
        nullptr, nullptr, nullptr, mask + (size_t)b * S * S, S, S, D);
    gemm_bt<2><<<dim3(S / 128, D / 128), 256, 0, stream>>>(
        Pb, VTb + (size_t)b * S * D, nullptr, (float*)d_out + (size_t)b * S * D,
        nullptr, nullptr, nullptr, nullptr, S, D, S);
  }
}

// Round 2
// 262.027 us; speedup vs baseline: 1.2721x; 1.2721x over previous
//
#include <hip/hip_runtime.h>
#include <hip/hip_bf16.h>

typedef unsigned short u16;
typedef __attribute__((ext_vector_type(8))) __bf16 bf16x8;
typedef __attribute__((ext_vector_type(4))) float f32x4;

#define DEV static __device__ __forceinline__

DEV u16 f2bf(float f) {
  union { float f; unsigned u; } c; c.f = f;
  unsigned r = c.u + 0x7fffu + ((c.u >> 16) & 1u);
  return (u16)(r >> 16);
}
DEV float fsig(float x) { return 1.f / (1.f + __expf(-x)); }

DEV void gload_lds16(const void* g, void* l) {
  __builtin_amdgcn_global_load_lds(
      (const __attribute__((address_space(1))) void*)g,
      (__attribute__((address_space(3))) void*)l, 16, 0, 0);
}

// fp32 -> bf16 elementwise (RNE), float4-vectorized
__global__ void cvt_bf16(const float4* __restrict__ src, u16* __restrict__ dst, int n4) {
  int i = blockIdx.x * blockDim.x + threadIdx.x;
  int stride = gridDim.x * blockDim.x;
  for (; i < n4; i += stride) {
    float4 v = src[i];
    union { u16 s[4]; unsigned long long q; } o;
    o.s[0] = f2bf(v.x); o.s[1] = f2bf(v.y); o.s[2] = f2bf(v.z); o.s[3] = f2bf(v.w);
    *(unsigned long long*)&dst[(size_t)i * 4] = o.q;
  }
}

// 3 weight matrices in one launch (z selects source), dst contiguous
__global__ void cvt_w3(const float4* __restrict__ s0, const float4* __restrict__ s1,
                       const float4* __restrict__ s2, u16* __restrict__ dst, int n4) {
  const float4* src = blockIdx.z == 0 ? s0 : (blockIdx.z == 1 ? s1 : s2);
  u16* d = dst + (size_t)blockIdx.z * n4 * 4;
  int i = blockIdx.x * blockDim.x + threadIdx.x;
  int stride = gridDim.x * blockDim.x;
  for (; i < n4; i += stride) {
    float4 v = src[i];
    union { u16 s[4]; unsigned long long q; } o;
    o.s[0] = f2bf(v.x); o.s[1] = f2bf(v.y); o.s[2] = f2bf(v.z); o.s[3] = f2bf(v.w);
    *(unsigned long long*)&d[(size_t)i * 4] = o.q;
  }
}

// 64x64-tile bf16 transpose: VT[d][k] = V[k][d], per batch (blockIdx.z)
__global__ __launch_bounds__(256) void transpose_bf16(
    const u16* __restrict__ V, u16* __restrict__ VT, int rows, int cols) {
  __shared__ u16 t[64][80];
  const u16* Vb = V + (size_t)blockIdx.z * rows * cols;
  u16* VTb = VT + (size_t)blockIdx.z * rows * cols;
  const int kb = blockIdx.x * 64, db = blockIdx.y * 64;
  const int tid = threadIdx.x;
  const int r = tid >> 3, c8 = (tid & 7) * 8;
#pragma unroll
  for (int it = 0; it < 2; it++) {
    int rr = r + it * 32;
    *(uint4*)&t[rr][c8] = *(const uint4*)&Vb[(size_t)(kb + rr) * cols + db + c8];
  }
  __syncthreads();
#pragma unroll
  for (int it = 0; it < 2; it++) {
    int d = (tid >> 3) + it * 32;
    int k0 = (tid & 7) * 8;
    union { u16 s[8]; uint4 q; } o;
#pragma unroll
    for (int j = 0; j < 8; j++) o.s[j] = t[k0 + j][d];
    *(uint4*)&VTb[(size_t)(db + d) * rows + kb + k0] = o.q;
  }
}

// C[M,N] = A[M,K] * Bt[N,K]^T  (bf16 in, fp32 acc), 128x128 tile, BK=64, 4 waves.
// EPI 0: QKV (z selects W/bias; Q scaled 1/32; A shared) -> bf16
// EPI 1: scores (z = batch: A,Bt,mask,C all offset): sigmoid(sigmoid(acc)*mask) -> bf16
// EPI 2: PV (z = batch): plain fp32 out
template <int EPI>
__global__ __launch_bounds__(256, 2) void gemm_bt(
    const u16* __restrict__ A, const u16* __restrict__ Bt,
    u16* __restrict__ Cb, float* __restrict__ Cf,
    const float* __restrict__ bias0, const float* __restrict__ bias1,
    const float* __restrict__ bias2, const float* __restrict__ mask,
    int M, int N, int K) {
  __shared__ __align__(16) u16 As[128 * 64];
  __shared__ __align__(16) u16 Bs[128 * 64];

  const int bm = blockIdx.x, bn = blockIdx.y, z = blockIdx.z;
  if (EPI == 0) {
    Bt += (size_t)z * N * K;
  } else {
    A += (size_t)z * M * K;
    Bt += (size_t)z * N * K;
    if (EPI == 1) mask += (size_t)z * M * N;
  }
  const size_t cofs = (size_t)z * M * N;
  const float* bias = (EPI == 0) ? (z == 0 ? bias0 : (z == 1 ? bias1 : bias2)) : nullptr;
  const float scale = (EPI == 0 && z == 0) ? 0.03125f : 1.0f;

  const int tid = threadIdx.x;
  const int wid = tid >> 6, lane = tid & 63;
  const int wr = wid >> 1, wc = wid & 1;
  const int l3 = lane >> 3, sl = lane & 7;
  const int srcslot = sl ^ l3;  // pre-swizzled global source slot (rule #21)

  const u16* Ag = A + (size_t)(bm * 128 + wid * 32 + l3) * K + srcslot * 8;
  const u16* Bg = Bt + (size_t)(bn * 128 + wid * 32 + l3) * K + srcslot * 8;
  u16* AsW = &As[wid * 32 * 64];
  u16* BsW = &Bs[wid * 32 * 64];

  f32x4 acc[4][4];
#pragma unroll
  for (int i = 0; i < 4; i++)
#pragma unroll
    for (int j = 0; j < 4; j++) acc[i][j] = (f32x4)(0.f);

  const int fr = lane & 15, kq = lane >> 4;

  for (int kt = 0; kt < K; kt += 64) {
#pragma unroll
    for (int i = 0; i < 4; i++) {
      gload_lds16(Ag + kt + i * 8 * K, AsW + i * 8 * 64);
      gload_lds16(Bg + kt + i * 8 * K, BsW + i * 8 * 64);
    }
    __syncthreads();
#pragma unroll
    for (int ks = 0; ks < 2; ks++) {
      bf16x8 af[4], bfr[4];
#pragma unroll
      for (int i = 0; i < 4; i++) {
        const int ra = wr * 64 + i * 16 + fr;
        af[i] = *(const bf16x8*)&As[ra * 64 + (((ks * 4 + kq) ^ (ra & 7)) * 8)];
        const int rb = wc * 64 + i * 16 + fr;
        bfr[i] = *(const bf16x8*)&Bs[rb * 64 + (((ks * 4 + kq) ^ (rb & 7)) * 8)];
      }
#pragma unroll
      for (int i = 0; i < 4; i++)
#pragma unroll
        for (int j = 0; j < 4; j++)
          acc[i][j] = __builtin_amdgcn_mfma_f32_16x16x32_bf16(af[i], bfr[j], acc[i][j], 0, 0, 0);
    }
    __syncthreads();
  }

  const int rbase = bm * 128 + wr * 64;
  const int cbase = bn * 128 + wc * 64;
#pragma unroll
  for (int i = 0; i < 4; i++)
#pragma unroll
    for (int j = 0; j < 4; j++) {
      const int col = cbase + j * 16 + fr;
#pragma unroll
      for (int r = 0; r < 4; r++) {
        const int row = rbase + i * 16 + kq * 4 + r;
        float v = acc[i][j][r];
        if (EPI == 0) {
          v = (v + bias[col]) * scale;
          Cb[cofs + (size_t)row * N + col] = f2bf(v);
        } else if (EPI == 1) {
          float m = mask[(size_t)row * N + col];
          Cb[cofs + (size_t)row * N + col] = f2bf(fsig(fsig(v) * m));
        } else {
          Cf[cofs + (size_t)row * N + col] = v;
        }
      }
    }
}

extern "C" void kernel_launch(void* const* d_in, const int* in_sizes, int n_in,
                              void* d_out, int out_size, void* d_ws, size_t ws_size,
                              hipStream_t stream) {
  const int B = 2, S = 4096, D = 1024;
  const float* hid  = (const float*)d_in[0];
  const float* mask = (const float*)d_in[1];
  const float* Wq = (const float*)d_in[2];
  const float* bq = (const float*)d_in[3];
  const float* Wk = (const float*)d_in[4];
  const float* bk = (const float*)d_in[5];
  const float* Wv = (const float*)d_in[6];
  const float* bv = (const float*)d_in[7];

  const size_t MT = (size_t)B * S * D;  // 8388608
  u16* hbf = (u16*)d_ws;                // MT
  u16* wbf = hbf + MT;                  // 3*D*D
  u16* Qb  = wbf + 3 * (size_t)D * D;   // MT  (Q,K,V contiguous: EPI0 z-offset)
  u16* Kb  = Qb + MT;
  u16* Vb  = Kb + MT;
  u16* VTb = Vb + MT;                   // MT
  u16* Pb  = VTb + MT;                  // B*S*S (both batches)

  // 1. converts (2 launches)
  cvt_bf16<<<2048, 256, 0, stream>>>((const float4*)hid, hbf, (int)(MT / 4));
  cvt_w3<<<dim3(512, 1, 3), 256, 0, stream>>>(
      (const float4*)Wq, (const float4*)Wk, (const float4*)Wv, wbf, D * D / 4);

  // 2. fused QKV projection: [8192,1024] x [1024,1024]^T, z = Q/K/V
  gemm_bt<0><<<dim3(B * S / 128, D / 128, 3), 256, 0, stream>>>(
      hbf, wbf, Qb, nullptr, bq, bk, bv, nullptr, B * S, D, D);

  // 3. V transpose per batch: VT[d][k]
  transpose_bf16<<<dim3(S / 64, D / 64, B), 256, 0, stream>>>(Vb, VTb, S, D);

  // 4. both batches concurrently: scores(+sigmoid) then P*V
  gemm_bt<1><<<dim3(S / 128, S / 128, B), 256, 0, stream>>>(
      Qb, Kb, Pb, nullptr, nullptr, nullptr, nullptr, mask, S, S, D);
  gemm_bt<2><<<dim3(S / 128, D / 128, B), 256, 0, stream>>>(
      Pb, VTb, nullptr, (float*)d_out, nullptr, nullptr, nullptr, nullptr, S, D, S);
}